// Round 1
// baseline (825.442 us; speedup 1.0000x reference)
//
#include <hip/hip_runtime.h>

#define BB 8
#define NN 4096
#define CC 256

typedef __attribute__((ext_vector_type(8))) short bfx8;
typedef __attribute__((ext_vector_type(4))) unsigned short usx4;
typedef __attribute__((ext_vector_type(4))) float fx4;

__device__ inline unsigned short f2bf(float f) {
  union { float f; unsigned u; } c; c.f = f;
  unsigned r = c.u + 0x7fffu + ((c.u >> 16) & 1u);
  return (unsigned short)(r >> 16);
}
__device__ inline float bf2f(unsigned short h) {
  union { unsigned u; float f; } c; c.u = ((unsigned)h) << 16;
  return c.f;
}
__device__ inline fx4 MFMA(bfx8 a, bfx8 b, fx4 c) {
  return __builtin_amdgcn_mfma_f32_16x16x32_bf16(a, b, c, 0, 0, 0);
}

// ---------------------------------------------------------------------------
// Kernel 0: transpose + hi/lo split the three weight matrices.
// Wt[m][n][k] = W_m[k][n], stored as bf16 hi and lo parts.
// ---------------------------------------------------------------------------
__global__ void wconv(const float* __restrict__ Wq, const float* __restrict__ Wk,
                      const float* __restrict__ Wv,
                      unsigned short* __restrict__ Wth, unsigned short* __restrict__ Wtl) {
  int m = blockIdx.y, n = blockIdx.x, k = threadIdx.x;
  const float* W = (m == 0) ? Wq : (m == 1) ? Wk : Wv;
  float v = W[k * CC + n];
  unsigned short h = f2bf(v);
  unsigned short lo = f2bf(v - bf2f(h));
  int o = (m * CC + n) * CC + k;
  Wth[o] = h; Wtl[o] = lo;
}

// ---------------------------------------------------------------------------
// Kernel 1: projection GEMM  Out_m = X @ W_m  (M=32768, N=256, K=256)
// split-bf16 3-pass MFMA (Xh*Wh + Xh*Wl + Xl*Wh), fp32 accumulate.
// m=0 -> Qh/Ql, m=1 -> Kh/Kl (row-major [B*N][C], hi/lo bf16)
// m=2 -> Vt bf16 transposed per batch: Vt[b][d][n]
// Block: 256 thr (4 waves), tile 64 rows x 256 cols, K chunked by 64.
// LDS: Xh[64][64] @0 (8K), Xl @8192, Wh[256][64] @16384 (32K), Wl @49152. 80KB.
// All LDS tiles: 128B rows, XOR swizzle byte^=((row&7)<<4).
// ---------------------------------------------------------------------------
__global__ __launch_bounds__(256, 2) void proj(
    const float* __restrict__ x,
    const unsigned short* __restrict__ Wth, const unsigned short* __restrict__ Wtl,
    unsigned short* __restrict__ Qh, unsigned short* __restrict__ Ql,
    unsigned short* __restrict__ Kh, unsigned short* __restrict__ Kl,
    unsigned short* __restrict__ Vt) {
  __shared__ char lds[81920];
  const int m = blockIdx.y;
  const int row0 = blockIdx.x * 64;
  const int t = threadIdx.x;
  const int wv = t >> 6, l = t & 63, lg = l >> 4, ll = l & 15;

  fx4 acc[16];
#pragma unroll
  for (int i = 0; i < 16; ++i) acc[i] = (fx4){0.f, 0.f, 0.f, 0.f};

  const unsigned short* Wmh = Wth + m * CC * CC;
  const unsigned short* Wml = Wtl + m * CC * CC;

  for (int kc = 0; kc < 4; ++kc) {
    __syncthreads();
    // stage X chunk [64 rows][64 c] fp32 -> hi/lo bf16 (16 threads/row, 4 floats each)
#pragma unroll
    for (int p = 0; p < 4; ++p) {
      int idx = p * 256 + t;
      int r = idx >> 4, c4 = (idx & 15) << 2;
      fx4 v = *(const fx4*)(x + (size_t)(row0 + r) * CC + kc * 64 + c4);
      usx4 hv, lv;
#pragma unroll
      for (int j = 0; j < 4; ++j) {
        unsigned short h = f2bf(v[j]);
        hv[j] = h; lv[j] = f2bf(v[j] - bf2f(h));
      }
      int bo = r * 128 + (((c4 << 1)) ^ ((r & 7) << 4));
      *(usx4*)(lds + bo) = hv;
      *(usx4*)(lds + 8192 + bo) = lv;
    }
    // stage Wt chunk [256 n][64 c] hi/lo (8 threads/row, 8 bf16 each)
#pragma unroll
    for (int p = 0; p < 8; ++p) {
      int idx = p * 256 + t;
      int n = idx >> 3, c8 = (idx & 7) << 3;
      int go = n * CC + kc * 64 + c8;
      bfx8 hv = *(const bfx8*)(Wmh + go);
      bfx8 lv = *(const bfx8*)(Wml + go);
      int bo = n * 128 + (((c8 << 1)) ^ ((n & 7) << 4));
      *(bfx8*)(lds + 16384 + bo) = hv;
      *(bfx8*)(lds + 49152 + bo) = lv;
    }
    __syncthreads();
#pragma unroll
    for (int ds = 0; ds < 2; ++ds) {
      int arow = wv * 16 + ll;
      int akb = ds * 64 + lg * 16;
      bfx8 ah = *(bfx8*)(lds + arow * 128 + (akb ^ ((arow & 7) << 4)));
      bfx8 al = *(bfx8*)(lds + 8192 + arow * 128 + (akb ^ ((arow & 7) << 4)));
#pragma unroll
      for (int nt = 0; nt < 16; ++nt) {
        int brow = nt * 16 + ll;
        int bo = brow * 128 + (akb ^ ((brow & 7) << 4));
        bfx8 bh = *(bfx8*)(lds + 16384 + bo);
        bfx8 bl = *(bfx8*)(lds + 49152 + bo);
        acc[nt] = MFMA(ah, bh, acc[nt]);
        acc[nt] = MFMA(ah, bl, acc[nt]);
        acc[nt] = MFMA(al, bh, acc[nt]);
      }
    }
  }
  // epilogue: C/D layout col=l&15, row=(l>>4)*4+r
#pragma unroll
  for (int nt = 0; nt < 16; ++nt) {
#pragma unroll
    for (int r = 0; r < 4; ++r) {
      float v = acc[nt][r];
      int grow = row0 + wv * 16 + lg * 4 + r;
      int col = nt * 16 + ll;
      if (m == 2) {
        int b = grow >> 12, nidx = grow & 4095;
        Vt[(((size_t)(b * CC + col)) << 12) + nidx] = f2bf(v);
      } else {
        unsigned short h = f2bf(v);
        unsigned short lo = f2bf(v - bf2f(h));
        size_t o = (size_t)grow * CC + col;
        if (m == 0) { Qh[o] = h; Ql[o] = lo; }
        else        { Kh[o] = h; Kl[o] = lo; }
      }
    }
  }
}

// ---------------------------------------------------------------------------
// Kernel 2: fused flash attention + gate.
// Block: 256 thr (4 waves), 64 q-rows (16/wave), KV tiles of 64 keys.
// S = (Qh+Ql)(Kh+Kl)^T via 3 bf16 MFMA passes (Kh staged, used for Qh & Ql
// passes; then K LDS restaged with Kl for the Qh pass). Online softmax in
// C/D layout with 16-lane shfl_xor row reductions. P -> wave-local LDS ->
// A-frags; PV from transposed V tile. Epilogue: out = x * (O/l).
// LDS: K tile 4x[64][64] sub-tiles @0 (32K), Vt tile [256][64] @32768 (32K),
// P [16][64] per wave @65536+wv*2048. 72KB -> 2 blocks/CU.
// ---------------------------------------------------------------------------
__global__ __launch_bounds__(256, 2) void attn(
    const float* __restrict__ x,
    const unsigned short* __restrict__ Qh, const unsigned short* __restrict__ Ql,
    const unsigned short* __restrict__ Kh, const unsigned short* __restrict__ Kl,
    const unsigned short* __restrict__ Vt, float* __restrict__ out) {
  __shared__ char lds[73728];
  const int b = blockIdx.y, q0 = blockIdx.x * 64;
  const int t = threadIdx.x, wv = t >> 6, l = t & 63, lg = l >> 4, ll = l & 15;

  // Q fragments (hi/lo) held in registers for the whole kernel
  bfx8 qh[8], qlo[8];
  {
    int qrow = q0 + wv * 16 + ll;
    const unsigned short* ph = Qh + ((size_t)(b * NN + qrow)) * CC + lg * 8;
    const unsigned short* pl = Ql + ((size_t)(b * NN + qrow)) * CC + lg * 8;
#pragma unroll
    for (int ds = 0; ds < 8; ++ds) {
      qh[ds]  = *(const bfx8*)(ph + ds * 32);
      qlo[ds] = *(const bfx8*)(pl + ds * 32);
    }
  }

  fx4 acc_o[16];
#pragma unroll
  for (int i = 0; i < 16; ++i) acc_o[i] = (fx4){0.f, 0.f, 0.f, 0.f};
  float mrow[4] = {-1e30f, -1e30f, -1e30f, -1e30f};
  float lrow[4] = {0.f, 0.f, 0.f, 0.f};

  const unsigned short* Khb = Kh + (size_t)b * NN * CC;
  const unsigned short* Klb = Kl + (size_t)b * NN * CC;
  const unsigned short* Vtb = Vt + (size_t)b * CC * NN;
  char* plds = lds + 65536 + wv * 2048;

  for (int kt = 0; kt < 64; ++kt) {
    const int key0 = kt * 64;
    __syncthreads();
    // stage Kh tile (as 4 d-chunk sub-tiles [64 key][64 d]) + Vt tile [256 d][64 key]
#pragma unroll
    for (int p = 0; p < 8; ++p) {
      int idx = p * 256 + t;
      int key = idx >> 5, db = (idx & 31) << 4;
      bfx8 kv = *(const bfx8*)((const char*)(Khb + (size_t)(key0 + key) * CC) + db);
      *(bfx8*)(lds + (db >> 7) * 8192 + key * 128 + ((db & 127) ^ ((key & 7) << 4))) = kv;
      int d = idx >> 3, kb = (idx & 7) << 4;
      bfx8 vv = *(const bfx8*)((const char*)(Vtb + (size_t)d * NN + key0) + kb);
      *(bfx8*)(lds + 32768 + d * 128 + (kb ^ ((d & 7) << 4))) = vv;
    }
    __syncthreads();
    fx4 accs[4];
#pragma unroll
    for (int i = 0; i < 4; ++i) accs[i] = (fx4){0.f, 0.f, 0.f, 0.f};
    // passes 1+2: Qh*Kh and Ql*Kh (reuse each K fragment for 2 MFMAs)
#pragma unroll
    for (int ds = 0; ds < 8; ++ds) {
      int dc = ds >> 1, dkb = (ds & 1) * 64 + lg * 16;
#pragma unroll
      for (int nt = 0; nt < 4; ++nt) {
        int krow = nt * 16 + ll;
        bfx8 bh = *(bfx8*)(lds + dc * 8192 + krow * 128 + (dkb ^ ((krow & 7) << 4)));
        accs[nt] = MFMA(qh[ds], bh, accs[nt]);
        accs[nt] = MFMA(qlo[ds], bh, accs[nt]);
      }
    }
    __syncthreads();
    // restage K LDS with Kl
#pragma unroll
    for (int p = 0; p < 8; ++p) {
      int idx = p * 256 + t;
      int key = idx >> 5, db = (idx & 31) << 4;
      bfx8 kv = *(const bfx8*)((const char*)(Klb + (size_t)(key0 + key) * CC) + db);
      *(bfx8*)(lds + (db >> 7) * 8192 + key * 128 + ((db & 127) ^ ((key & 7) << 4))) = kv;
    }
    __syncthreads();
    // pass 3: Qh*Kl
#pragma unroll
    for (int ds = 0; ds < 8; ++ds) {
      int dc = ds >> 1, dkb = (ds & 1) * 64 + lg * 16;
#pragma unroll
      for (int nt = 0; nt < 4; ++nt) {
        int krow = nt * 16 + ll;
        bfx8 bl = *(bfx8*)(lds + dc * 8192 + krow * 128 + (dkb ^ ((krow & 7) << 4)));
        accs[nt] = MFMA(qh[ds], bl, accs[nt]);
      }
    }
    // ---- online softmax (rows r=0..3 of this lane: row = lg*4+r) ----
    float pm[4];
#pragma unroll
    for (int r = 0; r < 4; ++r)
      pm[r] = fmaxf(fmaxf(accs[0][r], accs[1][r]), fmaxf(accs[2][r], accs[3][r]));
#pragma unroll
    for (int s = 1; s < 16; s <<= 1) {
#pragma unroll
      for (int r = 0; r < 4; ++r) pm[r] = fmaxf(pm[r], __shfl_xor(pm[r], s, 64));
    }
    float scl[4];
#pragma unroll
    for (int r = 0; r < 4; ++r) {
      float mn = fmaxf(mrow[r], pm[r]);
      scl[r] = __expf(mrow[r] - mn);
      mrow[r] = mn;
    }
    float rs[4] = {0.f, 0.f, 0.f, 0.f};
    float pvv[4][4];
#pragma unroll
    for (int nt = 0; nt < 4; ++nt)
#pragma unroll
      for (int r = 0; r < 4; ++r) {
        float e = __expf(accs[nt][r] - mrow[r]);
        pvv[nt][r] = e; rs[r] += e;
      }
#pragma unroll
    for (int s = 1; s < 16; s <<= 1) {
#pragma unroll
      for (int r = 0; r < 4; ++r) rs[r] += __shfl_xor(rs[r], s, 64);
    }
#pragma unroll
    for (int r = 0; r < 4; ++r) lrow[r] = lrow[r] * scl[r] + rs[r];
#pragma unroll
    for (int i = 0; i < 16; ++i)
#pragma unroll
      for (int r = 0; r < 4; ++r) acc_o[i][r] *= scl[r];
    // write P to wave-local LDS (C/D layout -> [16 row][64 key] swizzled)
#pragma unroll
    for (int nt = 0; nt < 4; ++nt)
#pragma unroll
      for (int r = 0; r < 4; ++r) {
        int prow = lg * 4 + r, pcol = nt * 16 + ll;
        *(unsigned short*)(plds + prow * 128 + (((pcol << 1)) ^ ((prow & 7) << 4))) =
            f2bf(pvv[nt][r]);
      }
    asm volatile("s_waitcnt lgkmcnt(0)" ::: "memory");
    // PV: acc_o += P @ V  (A from P LDS, B from transposed-V tile)
#pragma unroll
    for (int ks = 0; ks < 2; ++ks) {
      int kbyte = ks * 64 + lg * 16;
      bfx8 pa = *(bfx8*)(plds + ll * 128 + (kbyte ^ ((ll & 7) << 4)));
#pragma unroll
      for (int nt = 0; nt < 16; ++nt) {
        int vrow = nt * 16 + ll;
        bfx8 bv = *(bfx8*)(lds + 32768 + vrow * 128 + (kbyte ^ ((vrow & 7) << 4)));
        acc_o[nt] = MFMA(pa, bv, acc_o[nt]);
      }
    }
  }
  // epilogue: normalize, gate with x, store fp32
#pragma unroll
  for (int nt = 0; nt < 16; ++nt)
#pragma unroll
    for (int r = 0; r < 4; ++r) {
      int grow = q0 + wv * 16 + lg * 4 + r;
      int col = nt * 16 + ll;
      size_t o = ((size_t)(b * NN + grow)) * CC + col;
      out[o] = x[o] * (acc_o[nt][r] / lrow[r]);
    }
}

// ---------------------------------------------------------------------------
extern "C" void kernel_launch(void* const* d_in, const int* in_sizes, int n_in,
                              void* d_out, int out_size, void* d_ws, size_t ws_size,
                              hipStream_t stream) {
  const float* x  = (const float*)d_in[0];
  const float* Wq = (const float*)d_in[1];
  const float* Wk = (const float*)d_in[2];
  const float* Wv = (const float*)d_in[3];
  float* out = (float*)d_out;
  char* ws = (char*)d_ws;
  const size_t T = (size_t)BB * NN * CC * 2;  // 16 MiB per bf16 tensor
  unsigned short* Qh  = (unsigned short*)(ws);
  unsigned short* Ql  = (unsigned short*)(ws + T);
  unsigned short* Kh  = (unsigned short*)(ws + 2 * T);
  unsigned short* Kl  = (unsigned short*)(ws + 3 * T);
  unsigned short* Vt  = (unsigned short*)(ws + 4 * T);
  unsigned short* Wth = (unsigned short*)(ws + 5 * T);
  unsigned short* Wtl = (unsigned short*)(ws + 5 * T + (size_t)3 * CC * CC * 2);
  if (ws_size < 5 * T + (size_t)6 * CC * CC * 2) return;  // need ~81 MB scratch

  hipLaunchKernelGGL(wconv, dim3(256, 3), dim3(256), 0, stream, Wq, Wk, Wv, Wth, Wtl);
  hipLaunchKernelGGL(proj, dim3(512, 3), dim3(256), 0, stream,
                     x, Wth, Wtl, Qh, Ql, Kh, Kl, Vt);
  hipLaunchKernelGGL(attn, dim3(64, 8), dim3(256), 0, stream,
                     x, Qh, Ql, Kh, Kl, Vt, out);
}

// Round 4
// 366.549 us; speedup vs baseline: 2.2519x; 2.2519x over previous
//
#include <hip/hip_runtime.h>

#define BB 8
#define NN 4096
#define CC 256

typedef __attribute__((ext_vector_type(8))) short bfx8;
typedef __attribute__((ext_vector_type(4))) unsigned short usx4;
typedef __attribute__((ext_vector_type(4))) float fx4;
typedef _Float16 hfx8 __attribute__((ext_vector_type(8)));

__device__ inline unsigned short f2bf(float f) {
  union { float f; unsigned u; } c; c.f = f;
  unsigned r = c.u + 0x7fffu + ((c.u >> 16) & 1u);
  return (unsigned short)(r >> 16);
}
__device__ inline float bf2f(unsigned short h) {
  union { unsigned u; float f; } c; c.u = ((unsigned)h) << 16;
  return c.f;
}
__device__ inline unsigned short f2h(float f) {
  union { _Float16 h; unsigned short u; } c; c.h = (_Float16)f;
  return c.u;
}
__device__ inline fx4 MFMA(bfx8 a, bfx8 b, fx4 c) {
  return __builtin_amdgcn_mfma_f32_16x16x32_bf16(a, b, c, 0, 0, 0);
}
__device__ inline fx4 MFMAH(hfx8 a, hfx8 b, fx4 c) {
  return __builtin_amdgcn_mfma_f32_16x16x32_f16(a, b, c, 0, 0, 0);
}

// ---------------------------------------------------------------------------
// Kernel 0: transpose + hi/lo split the three weight matrices (bf16 parts).
// ---------------------------------------------------------------------------
__global__ void wconv(const float* __restrict__ Wq, const float* __restrict__ Wk,
                      const float* __restrict__ Wv,
                      unsigned short* __restrict__ Wth, unsigned short* __restrict__ Wtl) {
  int m = blockIdx.y, n = blockIdx.x, k = threadIdx.x;
  const float* W = (m == 0) ? Wq : (m == 1) ? Wk : Wv;
  float v = W[k * CC + n];
  unsigned short h = f2bf(v);
  unsigned short lo = f2bf(v - bf2f(h));
  int o = (m * CC + n) * CC + k;
  Wth[o] = h; Wtl[o] = lo;
}

// ---------------------------------------------------------------------------
// Kernel 1: projection GEMM  Out_m = X @ W_m  (M=32768, N=256, K=256)
// PASSES==3 (Q,K): split-bf16 3-pass MFMA, output single fp16 row-major.
// PASSES==1 (V):  1-pass bf16, output fp16 transposed per batch Vt[b][d][n].
// ---------------------------------------------------------------------------
template <int PASSES>
__global__ __launch_bounds__(256, 2) void proj(
    const float* __restrict__ x,
    const unsigned short* __restrict__ Wth, const unsigned short* __restrict__ Wtl,
    unsigned short* __restrict__ O0, unsigned short* __restrict__ O1) {
  __shared__ char lds[81920];
  const int m = (PASSES == 1) ? 2 : (int)blockIdx.y;
  const int row0 = blockIdx.x * 64;
  const int t = threadIdx.x;
  const int wv = t >> 6, l = t & 63, lg = l >> 4, ll = l & 15;

  fx4 acc[16];
#pragma unroll
  for (int i = 0; i < 16; ++i) acc[i] = (fx4){0.f, 0.f, 0.f, 0.f};

  const unsigned short* Wmh = Wth + m * CC * CC;
  const unsigned short* Wml = Wtl + m * CC * CC;

  for (int kc = 0; kc < 4; ++kc) {
    __syncthreads();
    // stage X chunk [64 rows][64 c] fp32 -> hi(/lo) bf16
#pragma unroll
    for (int p = 0; p < 4; ++p) {
      int idx = p * 256 + t;
      int r = idx >> 4, c4 = (idx & 15) << 2;
      fx4 v = *(const fx4*)(x + (size_t)(row0 + r) * CC + kc * 64 + c4);
      usx4 hv, lv;
#pragma unroll
      for (int j = 0; j < 4; ++j) {
        unsigned short h = f2bf(v[j]);
        hv[j] = h;
        if (PASSES == 3) lv[j] = f2bf(v[j] - bf2f(h));
      }
      int bo = r * 128 + (((c4 << 1)) ^ ((r & 7) << 4));
      *(usx4*)(lds + bo) = hv;
      if (PASSES == 3) *(usx4*)(lds + 8192 + bo) = lv;
    }
    // stage Wt chunk [256 n][64 c]
#pragma unroll
    for (int p = 0; p < 8; ++p) {
      int idx = p * 256 + t;
      int n = idx >> 3, c8 = (idx & 7) << 3;
      int go = n * CC + kc * 64 + c8;
      bfx8 hv = *(const bfx8*)(Wmh + go);
      int bo = n * 128 + (((c8 << 1)) ^ ((n & 7) << 4));
      *(bfx8*)(lds + 16384 + bo) = hv;
      if (PASSES == 3) {
        bfx8 lv = *(const bfx8*)(Wml + go);
        *(bfx8*)(lds + 49152 + bo) = lv;
      }
    }
    __syncthreads();
#pragma unroll
    for (int ds = 0; ds < 2; ++ds) {
      int arow = wv * 16 + ll;
      int akb = ds * 64 + lg * 16;
      bfx8 ah = *(bfx8*)(lds + arow * 128 + (akb ^ ((arow & 7) << 4)));
      bfx8 al;
      if (PASSES == 3) al = *(bfx8*)(lds + 8192 + arow * 128 + (akb ^ ((arow & 7) << 4)));
#pragma unroll
      for (int nt = 0; nt < 16; ++nt) {
        int brow = nt * 16 + ll;
        int bo = brow * 128 + (akb ^ ((brow & 7) << 4));
        bfx8 bh = *(bfx8*)(lds + 16384 + bo);
        acc[nt] = MFMA(ah, bh, acc[nt]);
        if (PASSES == 3) {
          bfx8 bl = *(bfx8*)(lds + 49152 + bo);
          acc[nt] = MFMA(ah, bl, acc[nt]);
          acc[nt] = MFMA(al, bh, acc[nt]);
        }
      }
    }
  }
  // epilogue: C/D layout col=l&15, row=(l>>4)*4+r
#pragma unroll
  for (int nt = 0; nt < 16; ++nt) {
#pragma unroll
    for (int r = 0; r < 4; ++r) {
      float v = acc[nt][r];
      int grow = row0 + wv * 16 + lg * 4 + r;
      int col = nt * 16 + ll;
      if (PASSES == 1) {
        int b = grow >> 12, nidx = grow & 4095;
        O0[(((size_t)(b * CC + col)) << 12) + nidx] = f2h(v);
      } else {
        size_t o = (size_t)grow * CC + col;
        (m == 0 ? O0 : O1)[o] = f2h(v);
      }
    }
  }
}

// ---------------------------------------------------------------------------
// Kernel 2: fused flash attention + gate, all-fp16 operands, fp32 accum.
// 256 thr (4 waves), 64 q-rows/block, KV tiles of 64 keys.
// Per tile: reg->LDS stage of K,V (prefetched last iter), 1-pass QK (32 MFMA),
// online softmax w/ defer-max (THR=8), P fp16 -> wave-local LDS, PV (32 MFMA).
// Next tile's K/V global loads issue right after the stage barrier (T14).
// LDS: K 4x[64key][64d] @0 (32K), Vt [256d][64key] @32768 (32K),
// P [16][64] per wave @65536+wv*2048 (8K). 72KB -> 2 blocks/CU.
// ---------------------------------------------------------------------------
__global__ __launch_bounds__(256, 2) void attn(
    const float* __restrict__ x,
    const unsigned short* __restrict__ Qf, const unsigned short* __restrict__ Kf,
    const unsigned short* __restrict__ Vt, float* __restrict__ out) {
  __shared__ char lds[73728];
  const int b = blockIdx.y, q0 = blockIdx.x * 64;
  const int t = threadIdx.x, wv = t >> 6, l = t & 63, lg = l >> 4, ll = l & 15;

  // Q fragments in registers for the whole kernel
  hfx8 qh[8];
  {
    int qrow = q0 + wv * 16 + ll;
    const unsigned short* ph = Qf + ((size_t)(b * NN + qrow)) * CC + lg * 8;
#pragma unroll
    for (int ds = 0; ds < 8; ++ds) qh[ds] = *(const hfx8*)(ph + ds * 32);
  }

  fx4 acc_o[16];
#pragma unroll
  for (int i = 0; i < 16; ++i) acc_o[i] = (fx4){0.f, 0.f, 0.f, 0.f};
  float mrow[4] = {-1e30f, -1e30f, -1e30f, -1e30f};
  float lrow[4] = {0.f, 0.f, 0.f, 0.f};

  const unsigned short* Kb = Kf + (size_t)b * NN * CC;
  const unsigned short* Vtb = Vt + (size_t)b * CC * NN;
  char* plds = lds + 65536 + wv * 2048;

  // per-thread staging geometry
  const int kkey = t >> 5;         // key = p*8 + kkey
  const int kdb  = (t & 31) << 4;  // byte offset in 512B key row
  const int vd   = t >> 3;         // d = p*32 + vd
  const int vkb  = (t & 7) << 4;   // byte offset in 128B d row

  bfx8 kreg[8], vreg[8];  // prefetch registers (raw fp16 bits)
#pragma unroll
  for (int p = 0; p < 8; ++p) {
    kreg[p] = *(const bfx8*)((const char*)(Kb + (size_t)(p * 8 + kkey) * CC) + kdb);
    vreg[p] = *(const bfx8*)((const char*)(Vtb + (size_t)(p * 32 + vd) * NN) + vkb);
  }

  for (int kt = 0; kt < 64; ++kt) {
    __syncthreads();  // prev tile's LDS reads done; prefetch regs landed (vmcnt drain)
    // write staged regs -> LDS
#pragma unroll
    for (int p = 0; p < 8; ++p) {
      int key = p * 8 + kkey;
      *(bfx8*)(lds + (kdb >> 7) * 8192 + key * 128 + ((kdb & 127) ^ ((key & 7) << 4))) = kreg[p];
      int d = p * 32 + vd;
      *(bfx8*)(lds + 32768 + d * 128 + (vkb ^ ((d & 7) << 4))) = vreg[p];
    }
    __syncthreads();
    // issue next tile's global loads; they complete under this tile's compute
    if (kt < 63) {
      const unsigned short* Kn = Kb + (size_t)(kt + 1) * 64 * CC;
      const unsigned short* Vn = Vtb + (kt + 1) * 64;
#pragma unroll
      for (int p = 0; p < 8; ++p) {
        kreg[p] = *(const bfx8*)((const char*)(Kn + (size_t)(p * 8 + kkey) * CC) + kdb);
        vreg[p] = *(const bfx8*)((const char*)(Vn + (size_t)(p * 32 + vd) * NN) + vkb);
      }
    }
    // QK^T: 1 fp16 pass
    fx4 accs[4];
#pragma unroll
    for (int i = 0; i < 4; ++i) accs[i] = (fx4){0.f, 0.f, 0.f, 0.f};
#pragma unroll
    for (int ds = 0; ds < 8; ++ds) {
      int dc = ds >> 1, dkb = (ds & 1) * 64 + lg * 16;
#pragma unroll
      for (int nt = 0; nt < 4; ++nt) {
        int krow = nt * 16 + ll;
        hfx8 bh = *(hfx8*)(lds + dc * 8192 + krow * 128 + (dkb ^ ((krow & 7) << 4)));
        accs[nt] = MFMAH(qh[ds], bh, accs[nt]);
      }
    }
    // ---- online softmax (rows r: row = lg*4+r, cols across 16-lane group) ----
    float pm[4];
#pragma unroll
    for (int r = 0; r < 4; ++r)
      pm[r] = fmaxf(fmaxf(accs[0][r], accs[1][r]), fmaxf(accs[2][r], accs[3][r]));
#pragma unroll
    for (int s = 1; s < 16; s <<= 1) {
#pragma unroll
      for (int r = 0; r < 4; ++r) pm[r] = fmaxf(pm[r], __shfl_xor(pm[r], s, 64));
    }
    // defer-max: only rescale when some row's max grew by > 8
    bool upd = false;
#pragma unroll
    for (int r = 0; r < 4; ++r) upd |= (pm[r] > mrow[r] + 8.f);
    if (__any(upd)) {
#pragma unroll
      for (int r = 0; r < 4; ++r) {
        float mn = fmaxf(mrow[r], pm[r]);
        float scl = __expf(mrow[r] - mn);
        mrow[r] = mn;
        lrow[r] *= scl;
#pragma unroll
        for (int i = 0; i < 16; ++i) acc_o[i][r] *= scl;
      }
    }
    float rs[4] = {0.f, 0.f, 0.f, 0.f};
#pragma unroll
    for (int nt = 0; nt < 4; ++nt)
#pragma unroll
      for (int r = 0; r < 4; ++r) {
        float e = __expf(accs[nt][r] - mrow[r]);  // bounded by e^8 under defer
        rs[r] += e;
        int prow = lg * 4 + r, pcol = nt * 16 + ll;
        *(unsigned short*)(plds + prow * 128 + (((pcol << 1)) ^ ((prow & 7) << 4))) = f2h(e);
      }
#pragma unroll
    for (int s = 1; s < 16; s <<= 1) {
#pragma unroll
      for (int r = 0; r < 4; ++r) rs[r] += __shfl_xor(rs[r], s, 64);
    }
#pragma unroll
    for (int r = 0; r < 4; ++r) lrow[r] += rs[r];
    // PV: acc_o += P @ V
#pragma unroll
    for (int ks = 0; ks < 2; ++ks) {
      int kbyte = ks * 64 + lg * 16;
      hfx8 pa = *(hfx8*)(plds + ll * 128 + (kbyte ^ ((ll & 7) << 4)));
#pragma unroll
      for (int nt = 0; nt < 16; ++nt) {
        int vrow = nt * 16 + ll;
        hfx8 bv = *(hfx8*)(lds + 32768 + vrow * 128 + (kbyte ^ ((vrow & 7) << 4)));
        acc_o[nt] = MFMAH(pa, bv, acc_o[nt]);
      }
    }
  }
  // epilogue: normalize, gate with x, store fp32
#pragma unroll
  for (int nt = 0; nt < 16; ++nt)
#pragma unroll
    for (int r = 0; r < 4; ++r) {
      int grow = q0 + wv * 16 + lg * 4 + r;
      int col = nt * 16 + ll;
      size_t o = ((size_t)(b * NN + grow)) * CC + col;
      out[o] = x[o] * (acc_o[nt][r] / lrow[r]);
    }
}

// ---------------------------------------------------------------------------
extern "C" void kernel_launch(void* const* d_in, const int* in_sizes, int n_in,
                              void* d_out, int out_size, void* d_ws, size_t ws_size,
                              hipStream_t stream) {
  const float* x  = (const float*)d_in[0];
  const float* Wq = (const float*)d_in[1];
  const float* Wk = (const float*)d_in[2];
  const float* Wv = (const float*)d_in[3];
  float* out = (float*)d_out;
  char* ws = (char*)d_ws;
  const size_t T = (size_t)BB * NN * CC * 2;  // 16 MiB per fp16 tensor
  unsigned short* Qf  = (unsigned short*)(ws);
  unsigned short* Kf  = (unsigned short*)(ws + T);
  unsigned short* Vt  = (unsigned short*)(ws + 2 * T);
  unsigned short* Wth = (unsigned short*)(ws + 3 * T);
  unsigned short* Wtl = (unsigned short*)(ws + 3 * T + (size_t)3 * CC * CC * 2);
  if (ws_size < 3 * T + (size_t)6 * CC * CC * 2) return;  // ~49 MB scratch

  hipLaunchKernelGGL(wconv, dim3(256, 3), dim3(256), 0, stream, Wq, Wk, Wv, Wth, Wtl);
  hipLaunchKernelGGL((proj<3>), dim3(512, 2), dim3(256), 0, stream, x, Wth, Wtl, Qf, Kf);
  hipLaunchKernelGGL((proj<1>), dim3(512, 1), dim3(256), 0, stream, x, Wth, Wtl, Vt, Vt);
  hipLaunchKernelGGL(attn, dim3(64, 8), dim3(256), 0, stream, x, Qf, Kf, Vt, out);
}